// Round 9
// baseline (232.243 us; speedup 1.0000x reference)
//
#include <hip/hip_runtime.h>
#include <hip/hip_bf16.h>
#include <hip/hip_fp16.h>

#define N_NODES 100000
#define E_EDGES 400000
#define B_SUB 2048
#define INIT_DIM 100
#define UFD 100
#define ENT_DIM 400
#define GCN 128
#define NR2 100
#define KPAD 416           // 400 rounded up to 13*32
#define NCH 13             // K chunks of 32
#define CHK 32             // k per chunk
#define CAP 64             // bucket capacity per dst

typedef __attribute__((ext_vector_type(8))) short shortx8;
typedef __attribute__((ext_vector_type(4))) float floatx4;

#define OUT_R_OFF ((long)B_SUB * GCN)
#define OUT_X_OFF ((long)(B_SUB + NR2) * GCN)

__device__ __forceinline__ unsigned short f2b(float f) {
    unsigned u = __float_as_uint(f);
    u += 0x7fffu + ((u >> 16) & 1u);   // RNE to bf16
    return (unsigned short)(u >> 16);
}
__device__ __forceinline__ unsigned pk2(float x, float y) {
    return (unsigned)f2b(x) | ((unsigned)f2b(y) << 16);
}
// single-instruction packed RNE convert (bit-identical to pk2; harness-verified)
__device__ __forceinline__ unsigned cvtpk2(float x, float y) {
    unsigned r;
    asm("v_cvt_pk_bf16_f32 %0, %1, %2" : "=v"(r) : "v"(x), "v"(y));
    return r;
}
__device__ __forceinline__ float blo(unsigned u) { return __uint_as_float(u << 16); }
__device__ __forceinline__ float bhi(unsigned u) { return __uint_as_float(u & 0xFFFF0000u); }

// fast tanh: 1 - 2/(e^{2x}+1). Exact at +-inf; fp error ~1e-7 << bf16 noise.
__device__ __forceinline__ float fast_tanh(float x) {
    float e2 = __expf(2.f * x);
    return 1.f - 2.f / (e2 + 1.f);
}

// ---------------- W transpose + fp32->bf16 (also zeroes bucket cursors) ----------------
__global__ void wt_kernel(const float* __restrict__ W, unsigned short* __restrict__ Wt,
                          int* __restrict__ cursor) {
    int idx = blockIdx.x * 256 + threadIdx.x;
    if (idx < GCN * KPAD) {
        int n = idx & 127, k = idx >> 7;
        unsigned short o = 0;
        if (k < ENT_DIM) o = f2b(W[(long)k * GCN + n]);
        Wt[(long)n * KPAD + k] = o;
    }
    if (idx < N_NODES) cursor[idx] = 0;
}

// ---------------- relation GEMMs (tiny, fp32) ----------------
__global__ __launch_bounds__(256) void rel_kernel(
        const float* __restrict__ init_rel, const float* __restrict__ Wr,
        const float* __restrict__ Wrel, const float* __restrict__ att_src,
        unsigned* __restrict__ rp_b, float* __restrict__ rproj_att,
        float* __restrict__ out_r) {
    int rel = blockIdx.x;
    int t = threadIdx.x;            // 0..255
    int tx = t & 127, kh = t >> 7;  // output col, k-half
    __shared__ float rl[ENT_DIM];
    __shared__ float p1[2][128], p2[2][128];
    __shared__ float accbuf[128];
    for (int k = t; k < ENT_DIM; k += 256) rl[k] = init_rel[(long)rel * ENT_DIM + k];
    __syncthreads();
    float a1 = 0.f, a2 = 0.f;
    {
        const float* wr = Wr + (long)(kh * 200) * GCN + tx;
        const float* wl = Wrel + (long)(kh * 200) * GCN + tx;
        const float* rv = rl + kh * 200;
#pragma unroll 8
        for (int k = 0; k < 200; ++k) {
            float v = rv[k];
            a1 += v * wr[(long)k * GCN];
            a2 += v * wl[(long)k * GCN];
        }
    }
    p1[kh][tx] = a1;
    p2[kh][tx] = a2;
    __syncthreads();
    if (t < 128) {
        float acc1 = p1[0][tx] + p1[1][tx];
        float acc2 = p2[0][tx] + p2[1][tx];
        out_r[rel * GCN + tx] = acc2;
        accbuf[tx] = acc1;
        int head = tx >> 6, d = tx & 63;
        float v = acc1 * att_src[head * 64 + d];
        for (int off = 32; off > 0; off >>= 1) v += __shfl_down(v, off, 64);
        if (d == 0) rproj_att[rel * 2 + head] = v;
    }
    __syncthreads();
    if (t < 64) rp_b[rel * 64 + t] = pk2(accbuf[t], accbuf[t + 64]);
}

// ---------------- node GEMM h = init_embed @ W via bf16 MFMA ----------------
// (R8 form, FROZEN: 8 rounds show it at its fabric-traffic floor ~42 us.)
__global__ __launch_bounds__(256) void hgemm_kernel(
        const float* __restrict__ id_embed, const float* __restrict__ gtab,
        const float* __restrict__ atab, const float* __restrict__ ltab,
        const int* __restrict__ ent_feature, const unsigned short* __restrict__ Wt,
        const float* __restrict__ att_src, const float* __restrict__ att_dst,
        unsigned* __restrict__ h_b, float* __restrict__ hsrc_att, float* __restrict__ hdst_att) {
    __shared__ __align__(16) unsigned short Bs[2][128 * CHK];  // 8 KB per buf

    int t = threadIdx.x;
    int w = t >> 6, lane = t & 63, quad = lane >> 4, l16 = lane & 15;
    int n0 = blockIdx.x * 128;

    int nrow0 = n0 + w * 16 + l16;
    int nc0 = nrow0 < N_NODES ? nrow0 : N_NODES - 1;
    int nrow1 = nrow0 + 64;
    int nc1 = nrow1 < N_NODES ? nrow1 : N_NODES - 1;
    const float* pid0 = id_embed + (long)nc0 * INIT_DIM;
    const float* pg0  = gtab + ent_feature[nc0 * 3] * UFD;
    const float* pa0  = atab + ent_feature[nc0 * 3 + 1] * UFD;
    const float* pl0  = ltab + ent_feature[nc0 * 3 + 2] * UFD;
    const float* pid1 = id_embed + (long)nc1 * INIT_DIM;
    const float* pg1  = gtab + ent_feature[nc1 * 3] * UFD;
    const float* pa1  = atab + ent_feature[nc1 * 3 + 1] * UFD;
    const float* pl1  = ltab + ent_feature[nc1 * 3 + 2] * UFD;

    int cB = t >> 2;
    int lB8 = ((t & 3) ^ ((t >> 3) & 3)) * 8;  // shorts offset within chunk
    const unsigned short* bsrc0 = Wt + (long)cB * KPAD + lB8;
    const unsigned short* bsrc1 = Wt + (long)(64 + cB) * KPAD + lB8;

#define SEG0(kg_) ((kg_) < 100 ? pid0 + (kg_) : \
                   (kg_) < 200 ? pg0 + ((kg_) - 100) : \
                   (kg_) < 300 ? pa0 + ((kg_) - 200) : \
                   (kg_) < 400 ? pl0 + ((kg_) - 300) : pid0)  // k>=400: zero Wt rows
#define SEG1(kg_) ((kg_) < 100 ? pid1 + (kg_) : \
                   (kg_) < 200 ? pg1 + ((kg_) - 100) : \
                   (kg_) < 300 ? pa1 + ((kg_) - 200) : \
                   (kg_) < 400 ? pl1 + ((kg_) - 300) : pid1)

#define STAGE(ch_, bi_) { \
    __builtin_amdgcn_global_load_lds( \
        (const __attribute__((address_space(1))) unsigned*)(bsrc0 + (ch_) * CHK), \
        (__attribute__((address_space(3))) unsigned*)((char*)&Bs[bi_][0] + w * 1024), 16, 0, 0); \
    __builtin_amdgcn_global_load_lds( \
        (const __attribute__((address_space(1))) unsigned*)(bsrc1 + (ch_) * CHK), \
        (__attribute__((address_space(3))) unsigned*)((char*)&Bs[bi_][0] + 4096 + w * 1024), 16, 0, 0); \
}

    floatx4 acc0[8], acc1[8];
#pragma unroll
    for (int c = 0; c < 8; ++c) {
        acc0[c] = (floatx4){0.f, 0.f, 0.f, 0.f};
        acc1[c] = (floatx4){0.f, 0.f, 0.f, 0.f};
    }

    int qB = quad ^ ((l16 >> 1) & 3);          // B read-side phys slot (swizzle)

    STAGE(0, 0);
    float4 va0 = *(const float4*)SEG0(quad * 8);
    float4 vb0 = *(const float4*)SEG0(quad * 8 + 4);
    float4 va1 = *(const float4*)SEG1(quad * 8);
    float4 vb1 = *(const float4*)SEG1(quad * 8 + 4);

#pragma unroll
    for (int ch = 0; ch < NCH; ++ch) {
        __syncthreads();   // vmcnt(0)+barrier: B(ch) landed everywhere; A(ch) in regs
        if (ch + 1 < NCH) STAGE(ch + 1, (ch & 1) ^ 1);   // fire-and-forget under compute
        uint4 u0, u1;
        u0.x = cvtpk2(va0.x, va0.y); u0.y = cvtpk2(va0.z, va0.w);
        u0.z = cvtpk2(vb0.x, vb0.y); u0.w = cvtpk2(vb0.z, vb0.w);
        u1.x = cvtpk2(va1.x, va1.y); u1.y = cvtpk2(va1.z, va1.w);
        u1.z = cvtpk2(vb1.x, vb1.y); u1.w = cvtpk2(vb1.z, vb1.w);
        shortx8 af0 = *(shortx8*)&u0;
        shortx8 af1 = *(shortx8*)&u1;
        if (ch + 1 < NCH) {                      // A(ch+1) prefetch under MFMAs
            int kg = (ch + 1) * CHK + quad * 8;
            va0 = *(const float4*)SEG0(kg);
            vb0 = *(const float4*)SEG0(kg + 4);
            va1 = *(const float4*)SEG1(kg);
            vb1 = *(const float4*)SEG1(kg + 4);
        }
#pragma unroll
        for (int c = 0; c < 8; ++c) {
            shortx8 b_ = *(const shortx8*)(&Bs[ch & 1][0] + (c * 16 + l16) * CHK + qB * 8);
            acc0[c] = __builtin_amdgcn_mfma_f32_16x16x32_bf16(af0, b_, acc0[c], 0, 0, 0);
            acc1[c] = __builtin_amdgcn_mfma_f32_16x16x32_bf16(af1, b_, acc1[c], 0, 0, 0);
        }
    }
#undef STAGE
#undef SEG0
#undef SEG1

    // epilogue: C/D layout col=lane&15 (-> c*16+l16), row=quad*4+reg (R0-verified)
    float attS_r[8], attD_r[8];
#pragma unroll
    for (int c = 0; c < 8; ++c) {
        attS_r[c] = att_src[c * 16 + l16];
        attD_r[c] = att_dst[c * 16 + l16];
    }
#define EPILOG(accA, rowoff_) { \
    int baseRow = n0 + (rowoff_) + w * 16 + quad * 4; \
    _Pragma("unroll") for (int i = 0; i < 4; ++i) { \
        int node = baseRow + i; \
        bool ok = node < N_NODES; \
        _Pragma("unroll") for (int c = 0; c < 4; ++c) \
            if (ok) h_b[(long)node * 64 + c * 16 + l16] = cvtpk2(accA[c][i], accA[c + 4][i]); \
        float s0 = 0.f, s1 = 0.f, d0 = 0.f, d1 = 0.f; \
        _Pragma("unroll") for (int c = 0; c < 8; ++c) { \
            float v = accA[c][i]; \
            if (c < 4) { s0 += v * attS_r[c]; d0 += v * attD_r[c]; } \
            else       { s1 += v * attS_r[c]; d1 += v * attD_r[c]; } \
        } \
        _Pragma("unroll") for (int m = 1; m < 16; m <<= 1) { \
            s0 += __shfl_xor(s0, m, 64); \
            s1 += __shfl_xor(s1, m, 64); \
            d0 += __shfl_xor(d0, m, 64); \
            d1 += __shfl_xor(d1, m, 64); \
        } \
        if (ok && l16 == 0) { \
            *(float2*)&hsrc_att[node * 2] = make_float2(s0, s1); \
            *(float2*)&hdst_att[node * 2] = make_float2(d0, d1); \
        } \
    } }
    EPILOG(acc0, 0)
    EPILOG(acc1, 64)
#undef EPILOG
}

// ---------------- edge fill: 2 edges/thread (2x MLP on the gather chain) ----------------
__global__ void fill_kernel(const int* __restrict__ edge_index, const int* __restrict__ edge_type,
                            int* __restrict__ cursor,
                            const float2* __restrict__ hsrc2, const float2* __restrict__ rpa2,
                            const float2* __restrict__ hdst2,
                            uint2* __restrict__ ebuf) {
    int e0 = blockIdx.x * 512 + threadIdx.x;
    int e1 = e0 + 256;
    bool ok0 = e0 < E_EDGES, ok1 = e1 < E_EDGES;
    int s0i = 0, d0i = 0, t0i = 0, s1i = 0, d1i = 0, t1i = 0;
    if (ok0) { s0i = edge_index[e0]; d0i = edge_index[E_EDGES + e0]; t0i = edge_type[e0]; }
    if (ok1) { s1i = edge_index[e1]; d1i = edge_index[E_EDGES + e1]; t1i = edge_type[e1]; }
    // all 6 gathers issue before use (independent -> MLP)
    float2 hs0 = hsrc2[s0i], hd0 = hdst2[d0i], ra0 = rpa2[t0i];
    float2 hs1 = hsrc2[s1i], hd1 = hdst2[d1i], ra1 = rpa2[t1i];
    if (ok0) {
        float x0 = hs0.x + ra0.x + hd0.x;
        float x1 = hs0.y + ra0.y + hd0.y;
        x0 = x0 > 0.f ? x0 : 0.2f * x0;
        x1 = x1 > 0.f ? x1 : 0.2f * x1;
        __half2 hh = __floats2half2_rn(__expf(x0), __expf(x1));
        union { __half2 h; unsigned u; } cv; cv.h = hh;
        int pos = atomicAdd(&cursor[d0i], 1);
        if (pos < CAP)
            ebuf[(long)d0i * CAP + pos] = make_uint2(((unsigned)t0i << 17) | (unsigned)s0i, cv.u);
    }
    if (ok1) {
        float x0 = hs1.x + ra1.x + hd1.x;
        float x1 = hs1.y + ra1.y + hd1.y;
        x0 = x0 > 0.f ? x0 : 0.2f * x0;
        x1 = x1 > 0.f ? x1 : 0.2f * x1;
        __half2 hh = __floats2half2_rn(__expf(x0), __expf(x1));
        union { __half2 h; unsigned u; } cv; cv.h = hh;
        int pos = atomicAdd(&cursor[d1i], 1);
        if (pos < CAP)
            ebuf[(long)d1i * CAP + pos] = make_uint2(((unsigned)t1i << 17) | (unsigned)s1i, cv.u);
    }
}

// ---------------- per-dst aggregation: wave per FOUR dsts + rp_b in LDS ----------------
// v4: (1) rp_b (25.6 KB) staged in LDS once per block -> half the global
// gathers per step become conflict-free LDS reads (lanes consecutive);
// (2) 4 dsts per wave -> 16 h_b gathers in flight (2x R5's MLP).
// Entry uint4 loads are wave-uniform (broadcast); predicated-off slots
// bit-zeroed at the entry (0-entry -> e=0, gathers hit valid row 0).
__global__ __launch_bounds__(256) void agg_kernel(
        const int* __restrict__ cursor, const uint2* __restrict__ ebuf,
        const unsigned* __restrict__ h_b, const unsigned* __restrict__ rp_b,
        float* __restrict__ out_x) {
    __shared__ unsigned rp_s[NR2 * 64];        // 25.6 KB
    int t = threadIdx.x;
    for (int i = t; i < NR2 * 64; i += 256) rp_s[i] = rp_b[i];
    int w = t >> 6, l = t & 63;
    int dstBase = (blockIdx.x * 4 + w) * 4;    // grid = 6250, exact (16 dsts/block)
    const uint4* base[4];
    uint4 q[4];
    int cnt[4];
#pragma unroll
    for (int d = 0; d < 4; ++d) {
        base[d] = (const uint4*)(ebuf + (long)(dstBase + d) * CAP);
        q[d] = base[d][0];                     // batch-0 loads alongside cursor loads
    }
#pragma unroll
    for (int d = 0; d < 4; ++d) {
        cnt[d] = cursor[dstBase + d];
        if (cnt[d] > CAP) cnt[d] = CAP;
    }
    int jm = max(max(cnt[0], cnt[1]), max(cnt[2], cnt[3]));
    __syncthreads();                           // rp_s ready

    float a0[4] = {0.f, 0.f, 0.f, 0.f}, a1[4] = {0.f, 0.f, 0.f, 0.f};
    float dn0[4] = {0.f, 0.f, 0.f, 0.f}, dn1[4] = {0.f, 0.f, 0.f, 0.f};

    for (int j = 0; j < jm; j += 2) {
        unsigned i0[4], e0u[4], i1[4], e1u[4];
#pragma unroll
        for (int d = 0; d < 4; ++d) {
            i0[d]  = j     < cnt[d] ? q[d].x : 0u;
            e0u[d] = j     < cnt[d] ? q[d].y : 0u;
            i1[d]  = j + 1 < cnt[d] ? q[d].z : 0u;
            e1u[d] = j + 1 < cnt[d] ? q[d].w : 0u;
        }
        if (j + 2 < jm) {
#pragma unroll
            for (int d = 0; d < 4; ++d) q[d] = base[d][(j >> 1) + 1];
        }
        unsigned hb0[4], hb1[4], rb0[4], rb1[4];
#pragma unroll
        for (int d = 0; d < 4; ++d) {          // 8 global gathers in flight
            hb0[d] = h_b[(long)(i0[d] & 0x1FFFF) * 64 + l];
            hb1[d] = h_b[(long)(i1[d] & 0x1FFFF) * 64 + l];
        }
#pragma unroll
        for (int d = 0; d < 4; ++d) {          // LDS reads (conflict-free)
            rb0[d] = rp_s[(i0[d] >> 17) * 64 + l];
            rb1[d] = rp_s[(i1[d] >> 17) * 64 + l];
        }
#pragma unroll
        for (int d = 0; d < 4; ++d) {
            union { __half2 h; unsigned u; } c0, c1;
            c0.u = e0u[d]; c1.u = e1u[d];
            float2 f0 = __half22float2(c0.h), f1 = __half22float2(c1.h);
            a0[d] += f0.x * (blo(hb0[d]) + blo(rb0[d])) + f1.x * (blo(hb1[d]) + blo(rb1[d]));
            a1[d] += f0.y * (bhi(hb0[d]) + bhi(rb0[d])) + f1.y * (bhi(hb1[d]) + bhi(rb1[d]));
            dn0[d] += f0.x + f1.x;
            dn1[d] += f0.y + f1.y;
        }
    }
#pragma unroll
    for (int d = 0; d < 4; ++d) {
        float r0 = __builtin_amdgcn_rcpf(dn0[d] + 1e-16f);
        float r1 = __builtin_amdgcn_rcpf(dn1[d] + 1e-16f);
        __builtin_nontemporal_store(fast_tanh(a0[d] * r0),
                                    &out_x[(long)(dstBase + d) * GCN + l]);
        __builtin_nontemporal_store(fast_tanh(a1[d] * r1),
                                    &out_x[(long)(dstBase + d) * GCN + 64 + l]);
    }
}

// ---------------- sub gather ----------------
__global__ void gather_kernel(const int* __restrict__ sub, const float* __restrict__ out_x,
                              float* __restrict__ out_sub) {
    int idx = blockIdx.x * blockDim.x + threadIdx.x;
    if (idx >= B_SUB * GCN) return;
    int b = idx >> 7, d = idx & 127;
    out_sub[idx] = out_x[(long)sub[b] * GCN + d];
}

extern "C" void kernel_launch(void* const* d_in, const int* in_sizes, int n_in,
                              void* d_out, int out_size, void* d_ws, size_t ws_size,
                              hipStream_t stream) {
    const int* edge_index = (const int*)d_in[0];
    const int* edge_type  = (const int*)d_in[1];
    const int* ent_feature = (const int*)d_in[3];
    const int* sub = (const int*)d_in[4];
    const float* id_embed = (const float*)d_in[7];
    const float* gtab = (const float*)d_in[8];
    const float* atab = (const float*)d_in[9];
    const float* ltab = (const float*)d_in[10];
    const float* init_rel = (const float*)d_in[11];
    const float* W = (const float*)d_in[12];
    const float* Wr = (const float*)d_in[13];
    const float* att_src = (const float*)d_in[14];
    const float* att_dst = (const float*)d_in[15];
    const float* Wrel = (const float*)d_in[16];

    char* ws = (char*)d_ws;
    unsigned* h_b = (unsigned*)ws;                          ws += (long)N_NODES * 64 * 4;    // 25.6 MB
    unsigned* rp_b = (unsigned*)ws;                         ws += (long)NR2 * 64 * 4;
    float* rproj_att = (float*)ws;                          ws += NR2 * 2 * 4;
    float* hsrc_att = (float*)ws;                           ws += (long)N_NODES * 2 * 4;
    float* hdst_att = (float*)ws;                           ws += (long)N_NODES * 2 * 4;
    unsigned short* Wt = (unsigned short*)ws;               ws += (long)GCN * KPAD * 2;
    int* cursor = (int*)ws;                                 ws += (long)N_NODES * 4;
    uint2* ebuf = (uint2*)ws;                               ws += (long)N_NODES * CAP * 8;   // 51.2 MB

    float* out = (float*)d_out;
    float* out_sub = out;
    float* out_r = out + OUT_R_OFF;
    float* out_x = out + OUT_X_OFF;

    const int NB = (N_NODES + 255) / 256;   // 391

    wt_kernel<<<NB, 256, 0, stream>>>(W, Wt, cursor);       // also zeroes cursor
    rel_kernel<<<NR2, 256, 0, stream>>>(init_rel, Wr, Wrel, att_src, rp_b, rproj_att, out_r);
    hgemm_kernel<<<(N_NODES + 127) / 128, 256, 0, stream>>>(id_embed, gtab, atab, ltab,
                                                            ent_feature, Wt, att_src, att_dst,
                                                            h_b, hsrc_att, hdst_att);
    fill_kernel<<<(E_EDGES + 511) / 512, 256, 0, stream>>>(edge_index, edge_type, cursor,
                                                           (const float2*)hsrc_att,
                                                           (const float2*)rproj_att,
                                                           (const float2*)hdst_att, ebuf);
    agg_kernel<<<N_NODES / 16, 256, 0, stream>>>(cursor, ebuf, h_b, rp_b, out_x);
    gather_kernel<<<(B_SUB * GCN + 255) / 256, 256, 0, stream>>>(sub, out_x, out_sub);
}

// Round 10
// 214.092 us; speedup vs baseline: 1.0848x; 1.0848x over previous
//
#include <hip/hip_runtime.h>
#include <hip/hip_bf16.h>
#include <hip/hip_fp16.h>

#define N_NODES 100000
#define E_EDGES 400000
#define B_SUB 2048
#define INIT_DIM 100
#define UFD 100
#define ENT_DIM 400
#define GCN 128
#define NR2 100
#define KPAD 416           // 400 rounded up to 13*32
#define NCH 13             // K chunks of 32
#define CHK 32             // k per chunk
#define CAP 64             // bucket capacity per dst

typedef __attribute__((ext_vector_type(8))) short shortx8;
typedef __attribute__((ext_vector_type(4))) float floatx4;

#define OUT_R_OFF ((long)B_SUB * GCN)
#define OUT_X_OFF ((long)(B_SUB + NR2) * GCN)

__device__ __forceinline__ unsigned short f2b(float f) {
    unsigned u = __float_as_uint(f);
    u += 0x7fffu + ((u >> 16) & 1u);   // RNE to bf16
    return (unsigned short)(u >> 16);
}
__device__ __forceinline__ unsigned pk2(float x, float y) {
    return (unsigned)f2b(x) | ((unsigned)f2b(y) << 16);
}
// single-instruction packed RNE convert (bit-identical to pk2; harness-verified)
__device__ __forceinline__ unsigned cvtpk2(float x, float y) {
    unsigned r;
    asm("v_cvt_pk_bf16_f32 %0, %1, %2" : "=v"(r) : "v"(x), "v"(y));
    return r;
}
__device__ __forceinline__ float blo(unsigned u) { return __uint_as_float(u << 16); }
__device__ __forceinline__ float bhi(unsigned u) { return __uint_as_float(u & 0xFFFF0000u); }

// fast tanh: 1 - 2/(e^{2x}+1). Exact at +-inf; fp error ~1e-7 << bf16 noise.
__device__ __forceinline__ float fast_tanh(float x) {
    float e2 = __expf(2.f * x);
    return 1.f - 2.f / (e2 + 1.f);
}

// ---------------- merged: relation GEMMs (blocks 0..NR2-1) + W transpose &
// cursor zero (blocks NR2..) — independent work, one launch ----------------
__global__ __launch_bounds__(256) void wtrel_kernel(
        const float* __restrict__ W, unsigned short* __restrict__ Wt,
        int* __restrict__ cursor,
        const float* __restrict__ init_rel, const float* __restrict__ Wr,
        const float* __restrict__ Wrel, const float* __restrict__ att_src,
        unsigned* __restrict__ rp_b, float* __restrict__ rproj_att,
        float* __restrict__ out_r) {
    __shared__ float rl[ENT_DIM];
    __shared__ float p1[2][128], p2[2][128];
    __shared__ float accbuf[128];
    int t = threadIdx.x;
    if (blockIdx.x >= NR2) {
        // ---- wt part ----
        int idx = (blockIdx.x - NR2) * 256 + t;
        if (idx < GCN * KPAD) {
            int n = idx & 127, k = idx >> 7;
            unsigned short o = 0;
            if (k < ENT_DIM) o = f2b(W[(long)k * GCN + n]);
            Wt[(long)n * KPAD + k] = o;
        }
        if (idx < N_NODES) cursor[idx] = 0;
        return;
    }
    // ---- rel part (k split 2-way + unroll 8) ----
    int rel = blockIdx.x;
    int tx = t & 127, kh = t >> 7;  // output col, k-half
    for (int k = t; k < ENT_DIM; k += 256) rl[k] = init_rel[(long)rel * ENT_DIM + k];
    __syncthreads();
    float a1 = 0.f, a2 = 0.f;
    {
        const float* wr = Wr + (long)(kh * 200) * GCN + tx;
        const float* wl = Wrel + (long)(kh * 200) * GCN + tx;
        const float* rv = rl + kh * 200;
#pragma unroll 8
        for (int k = 0; k < 200; ++k) {
            float v = rv[k];
            a1 += v * wr[(long)k * GCN];
            a2 += v * wl[(long)k * GCN];
        }
    }
    p1[kh][tx] = a1;
    p2[kh][tx] = a2;
    __syncthreads();
    if (t < 128) {
        float acc1 = p1[0][tx] + p1[1][tx];
        float acc2 = p2[0][tx] + p2[1][tx];
        out_r[rel * GCN + tx] = acc2;
        accbuf[tx] = acc1;
        int head = tx >> 6, d = tx & 63;
        float v = acc1 * att_src[head * 64 + d];
        for (int off = 32; off > 0; off >>= 1) v += __shfl_down(v, off, 64);
        if (d == 0) rproj_att[rel * 2 + head] = v;
    }
    __syncthreads();
    if (t < 64) rp_b[rel * 64 + t] = pk2(accbuf[t], accbuf[t + 64]);
}

// ---------------- node GEMM h = init_embed @ W via bf16 MFMA ----------------
// (R8 form, FROZEN: 8 rounds show it at its fabric-traffic floor ~42 us.)
__global__ __launch_bounds__(256) void hgemm_kernel(
        const float* __restrict__ id_embed, const float* __restrict__ gtab,
        const float* __restrict__ atab, const float* __restrict__ ltab,
        const int* __restrict__ ent_feature, const unsigned short* __restrict__ Wt,
        const float* __restrict__ att_src, const float* __restrict__ att_dst,
        unsigned* __restrict__ h_b, float* __restrict__ hsrc_att, float* __restrict__ hdst_att) {
    __shared__ __align__(16) unsigned short Bs[2][128 * CHK];  // 8 KB per buf

    int t = threadIdx.x;
    int w = t >> 6, lane = t & 63, quad = lane >> 4, l16 = lane & 15;
    int n0 = blockIdx.x * 128;

    int nrow0 = n0 + w * 16 + l16;
    int nc0 = nrow0 < N_NODES ? nrow0 : N_NODES - 1;
    int nrow1 = nrow0 + 64;
    int nc1 = nrow1 < N_NODES ? nrow1 : N_NODES - 1;
    const float* pid0 = id_embed + (long)nc0 * INIT_DIM;
    const float* pg0  = gtab + ent_feature[nc0 * 3] * UFD;
    const float* pa0  = atab + ent_feature[nc0 * 3 + 1] * UFD;
    const float* pl0  = ltab + ent_feature[nc0 * 3 + 2] * UFD;
    const float* pid1 = id_embed + (long)nc1 * INIT_DIM;
    const float* pg1  = gtab + ent_feature[nc1 * 3] * UFD;
    const float* pa1  = atab + ent_feature[nc1 * 3 + 1] * UFD;
    const float* pl1  = ltab + ent_feature[nc1 * 3 + 2] * UFD;

    int cB = t >> 2;
    int lB8 = ((t & 3) ^ ((t >> 3) & 3)) * 8;  // shorts offset within chunk
    const unsigned short* bsrc0 = Wt + (long)cB * KPAD + lB8;
    const unsigned short* bsrc1 = Wt + (long)(64 + cB) * KPAD + lB8;

#define SEG0(kg_) ((kg_) < 100 ? pid0 + (kg_) : \
                   (kg_) < 200 ? pg0 + ((kg_) - 100) : \
                   (kg_) < 300 ? pa0 + ((kg_) - 200) : \
                   (kg_) < 400 ? pl0 + ((kg_) - 300) : pid0)  // k>=400: zero Wt rows
#define SEG1(kg_) ((kg_) < 100 ? pid1 + (kg_) : \
                   (kg_) < 200 ? pg1 + ((kg_) - 100) : \
                   (kg_) < 300 ? pa1 + ((kg_) - 200) : \
                   (kg_) < 400 ? pl1 + ((kg_) - 300) : pid1)

#define STAGE(ch_, bi_) { \
    __builtin_amdgcn_global_load_lds( \
        (const __attribute__((address_space(1))) unsigned*)(bsrc0 + (ch_) * CHK), \
        (__attribute__((address_space(3))) unsigned*)((char*)&Bs[bi_][0] + w * 1024), 16, 0, 0); \
    __builtin_amdgcn_global_load_lds( \
        (const __attribute__((address_space(1))) unsigned*)(bsrc1 + (ch_) * CHK), \
        (__attribute__((address_space(3))) unsigned*)((char*)&Bs[bi_][0] + 4096 + w * 1024), 16, 0, 0); \
}

    floatx4 acc0[8], acc1[8];
#pragma unroll
    for (int c = 0; c < 8; ++c) {
        acc0[c] = (floatx4){0.f, 0.f, 0.f, 0.f};
        acc1[c] = (floatx4){0.f, 0.f, 0.f, 0.f};
    }

    int qB = quad ^ ((l16 >> 1) & 3);          // B read-side phys slot (swizzle)

    STAGE(0, 0);
    float4 va0 = *(const float4*)SEG0(quad * 8);
    float4 vb0 = *(const float4*)SEG0(quad * 8 + 4);
    float4 va1 = *(const float4*)SEG1(quad * 8);
    float4 vb1 = *(const float4*)SEG1(quad * 8 + 4);

#pragma unroll
    for (int ch = 0; ch < NCH; ++ch) {
        __syncthreads();   // vmcnt(0)+barrier: B(ch) landed everywhere; A(ch) in regs
        if (ch + 1 < NCH) STAGE(ch + 1, (ch & 1) ^ 1);   // fire-and-forget under compute
        uint4 u0, u1;
        u0.x = cvtpk2(va0.x, va0.y); u0.y = cvtpk2(va0.z, va0.w);
        u0.z = cvtpk2(vb0.x, vb0.y); u0.w = cvtpk2(vb0.z, vb0.w);
        u1.x = cvtpk2(va1.x, va1.y); u1.y = cvtpk2(va1.z, va1.w);
        u1.z = cvtpk2(vb1.x, vb1.y); u1.w = cvtpk2(vb1.z, vb1.w);
        shortx8 af0 = *(shortx8*)&u0;
        shortx8 af1 = *(shortx8*)&u1;
        if (ch + 1 < NCH) {                      // A(ch+1) prefetch under MFMAs
            int kg = (ch + 1) * CHK + quad * 8;
            va0 = *(const float4*)SEG0(kg);
            vb0 = *(const float4*)SEG0(kg + 4);
            va1 = *(const float4*)SEG1(kg);
            vb1 = *(const float4*)SEG1(kg + 4);
        }
#pragma unroll
        for (int c = 0; c < 8; ++c) {
            shortx8 b_ = *(const shortx8*)(&Bs[ch & 1][0] + (c * 16 + l16) * CHK + qB * 8);
            acc0[c] = __builtin_amdgcn_mfma_f32_16x16x32_bf16(af0, b_, acc0[c], 0, 0, 0);
            acc1[c] = __builtin_amdgcn_mfma_f32_16x16x32_bf16(af1, b_, acc1[c], 0, 0, 0);
        }
    }
#undef STAGE
#undef SEG0
#undef SEG1

    // epilogue: C/D layout col=lane&15 (-> c*16+l16), row=quad*4+reg (R0-verified)
    float attS_r[8], attD_r[8];
#pragma unroll
    for (int c = 0; c < 8; ++c) {
        attS_r[c] = att_src[c * 16 + l16];
        attD_r[c] = att_dst[c * 16 + l16];
    }
#define EPILOG(accA, rowoff_) { \
    int baseRow = n0 + (rowoff_) + w * 16 + quad * 4; \
    _Pragma("unroll") for (int i = 0; i < 4; ++i) { \
        int node = baseRow + i; \
        bool ok = node < N_NODES; \
        _Pragma("unroll") for (int c = 0; c < 4; ++c) \
            if (ok) h_b[(long)node * 64 + c * 16 + l16] = cvtpk2(accA[c][i], accA[c + 4][i]); \
        float s0 = 0.f, s1 = 0.f, d0 = 0.f, d1 = 0.f; \
        _Pragma("unroll") for (int c = 0; c < 8; ++c) { \
            float v = accA[c][i]; \
            if (c < 4) { s0 += v * attS_r[c]; d0 += v * attD_r[c]; } \
            else       { s1 += v * attS_r[c]; d1 += v * attD_r[c]; } \
        } \
        _Pragma("unroll") for (int m = 1; m < 16; m <<= 1) { \
            s0 += __shfl_xor(s0, m, 64); \
            s1 += __shfl_xor(s1, m, 64); \
            d0 += __shfl_xor(d0, m, 64); \
            d1 += __shfl_xor(d1, m, 64); \
        } \
        if (ok && l16 == 0) { \
            *(float2*)&hsrc_att[node * 2] = make_float2(s0, s1); \
            *(float2*)&hdst_att[node * 2] = make_float2(d0, d1); \
        } \
    } }
    EPILOG(acc0, 0)
    EPILOG(acc1, 64)
#undef EPILOG
}

// ---------------- edge fill: 2 edges/thread (2x MLP on the gather chain) ----------------
__global__ void fill_kernel(const int* __restrict__ edge_index, const int* __restrict__ edge_type,
                            int* __restrict__ cursor,
                            const float2* __restrict__ hsrc2, const float2* __restrict__ rpa2,
                            const float2* __restrict__ hdst2,
                            uint2* __restrict__ ebuf) {
    int e0 = blockIdx.x * 512 + threadIdx.x;
    int e1 = e0 + 256;
    bool ok0 = e0 < E_EDGES, ok1 = e1 < E_EDGES;
    int s0i = 0, d0i = 0, t0i = 0, s1i = 0, d1i = 0, t1i = 0;
    if (ok0) { s0i = edge_index[e0]; d0i = edge_index[E_EDGES + e0]; t0i = edge_type[e0]; }
    if (ok1) { s1i = edge_index[e1]; d1i = edge_index[E_EDGES + e1]; t1i = edge_type[e1]; }
    // all 6 gathers issue before use (independent -> MLP)
    float2 hs0 = hsrc2[s0i], hd0 = hdst2[d0i], ra0 = rpa2[t0i];
    float2 hs1 = hsrc2[s1i], hd1 = hdst2[d1i], ra1 = rpa2[t1i];
    if (ok0) {
        float x0 = hs0.x + ra0.x + hd0.x;
        float x1 = hs0.y + ra0.y + hd0.y;
        x0 = x0 > 0.f ? x0 : 0.2f * x0;
        x1 = x1 > 0.f ? x1 : 0.2f * x1;
        __half2 hh = __floats2half2_rn(__expf(x0), __expf(x1));
        union { __half2 h; unsigned u; } cv; cv.h = hh;
        int pos = atomicAdd(&cursor[d0i], 1);
        if (pos < CAP)
            ebuf[(long)d0i * CAP + pos] = make_uint2(((unsigned)t0i << 17) | (unsigned)s0i, cv.u);
    }
    if (ok1) {
        float x0 = hs1.x + ra1.x + hd1.x;
        float x1 = hs1.y + ra1.y + hd1.y;
        x0 = x0 > 0.f ? x0 : 0.2f * x0;
        x1 = x1 > 0.f ? x1 : 0.2f * x1;
        __half2 hh = __floats2half2_rn(__expf(x0), __expf(x1));
        union { __half2 h; unsigned u; } cv; cv.h = hh;
        int pos = atomicAdd(&cursor[d1i], 1);
        if (pos < CAP)
            ebuf[(long)d1i * CAP + pos] = make_uint2(((unsigned)t1i << 17) | (unsigned)s1i, cv.u);
    }
}

// ---------------- per-dst aggregation: wave per TWO dsts (R5 form, proven) ----------------
__global__ __launch_bounds__(256) void agg_kernel(
        const int* __restrict__ cursor, const uint2* __restrict__ ebuf,
        const unsigned* __restrict__ h_b, const unsigned* __restrict__ rp_b,
        float* __restrict__ out_x) {
    int w = threadIdx.x >> 6, l = threadIdx.x & 63;
    int dstA = (blockIdx.x * 4 + w) * 2;      // grid = 12500 blocks, exact coverage
    int dstB = dstA + 1;
    const uint4* baseA = (const uint4*)(ebuf + (long)dstA * CAP);  // 2 entries / uint4
    const uint4* baseB = (const uint4*)(ebuf + (long)dstB * CAP);
    // batch 0 loads issue alongside cursor loads (no dependence)
    uint4 qA = baseA[0];
    uint4 qB = baseB[0];
    int cntA = cursor[dstA]; if (cntA > CAP) cntA = CAP;
    int cntB = cursor[dstB]; if (cntB > CAP) cntB = CAP;
    int jm = cntA > cntB ? cntA : cntB;

    float aA0 = 0.f, aA1 = 0.f, dA0 = 0.f, dA1 = 0.f;
    float aB0 = 0.f, aB1 = 0.f, dB0 = 0.f, dB1 = 0.f;

    for (int j = 0; j < jm; j += 2) {
        // bit-zero predicated-off entries
        unsigned iA0 = j     < cntA ? qA.x : 0u, eA0u = j     < cntA ? qA.y : 0u;
        unsigned iA1 = j + 1 < cntA ? qA.z : 0u, eA1u = j + 1 < cntA ? qA.w : 0u;
        unsigned iB0 = j     < cntB ? qB.x : 0u, eB0u = j     < cntB ? qB.y : 0u;
        unsigned iB1 = j + 1 < cntB ? qB.z : 0u, eB1u = j + 1 < cntB ? qB.w : 0u;
        // prefetch next batch (low pressure; loop-carried)
        if (j + 2 < jm) {
            qA = baseA[(j >> 1) + 1];
            qB = baseB[(j >> 1) + 1];
        }
        // 8 gathers in flight
        unsigned hbA0 = h_b[(long)(iA0 & 0x1FFFF) * 64 + l];
        unsigned hbA1 = h_b[(long)(iA1 & 0x1FFFF) * 64 + l];
        unsigned hbB0 = h_b[(long)(iB0 & 0x1FFFF) * 64 + l];
        unsigned hbB1 = h_b[(long)(iB1 & 0x1FFFF) * 64 + l];
        unsigned rbA0 = rp_b[(iA0 >> 17) * 64 + l];
        unsigned rbA1 = rp_b[(iA1 >> 17) * 64 + l];
        unsigned rbB0 = rp_b[(iB0 >> 17) * 64 + l];
        unsigned rbB1 = rp_b[(iB1 >> 17) * 64 + l];
        union { __half2 h; unsigned u; } cA0, cA1, cB0, cB1;
        cA0.u = eA0u; cA1.u = eA1u; cB0.u = eB0u; cB1.u = eB1u;
        float2 fA0 = __half22float2(cA0.h), fA1 = __half22float2(cA1.h);
        float2 fB0 = __half22float2(cB0.h), fB1 = __half22float2(cB1.h);
        aA0 += fA0.x * (blo(hbA0) + blo(rbA0)) + fA1.x * (blo(hbA1) + blo(rbA1));
        aA1 += fA0.y * (bhi(hbA0) + bhi(rbA0)) + fA1.y * (bhi(hbA1) + bhi(rbA1));
        aB0 += fB0.x * (blo(hbB0) + blo(rbB0)) + fB1.x * (blo(hbB1) + blo(rbB1));
        aB1 += fB0.y * (bhi(hbB0) + bhi(rbB0)) + fB1.y * (bhi(hbB1) + bhi(rbB1));
        dA0 += fA0.x + fA1.x;  dA1 += fA0.y + fA1.y;
        dB0 += fB0.x + fB1.x;  dB1 += fB0.y + fB1.y;
    }
    float rA0 = __builtin_amdgcn_rcpf(dA0 + 1e-16f);
    float rA1 = __builtin_amdgcn_rcpf(dA1 + 1e-16f);
    float rB0 = __builtin_amdgcn_rcpf(dB0 + 1e-16f);
    float rB1 = __builtin_amdgcn_rcpf(dB1 + 1e-16f);
    __builtin_nontemporal_store(fast_tanh(aA0 * rA0), &out_x[(long)dstA * GCN + l]);
    __builtin_nontemporal_store(fast_tanh(aA1 * rA1), &out_x[(long)dstA * GCN + 64 + l]);
    __builtin_nontemporal_store(fast_tanh(aB0 * rB0), &out_x[(long)dstB * GCN + l]);
    __builtin_nontemporal_store(fast_tanh(aB1 * rB1), &out_x[(long)dstB * GCN + 64 + l]);
}

// ---------------- sub gather ----------------
__global__ void gather_kernel(const int* __restrict__ sub, const float* __restrict__ out_x,
                              float* __restrict__ out_sub) {
    int idx = blockIdx.x * blockDim.x + threadIdx.x;
    if (idx >= B_SUB * GCN) return;
    int b = idx >> 7, d = idx & 127;
    out_sub[idx] = out_x[(long)sub[b] * GCN + d];
}

extern "C" void kernel_launch(void* const* d_in, const int* in_sizes, int n_in,
                              void* d_out, int out_size, void* d_ws, size_t ws_size,
                              hipStream_t stream) {
    const int* edge_index = (const int*)d_in[0];
    const int* edge_type  = (const int*)d_in[1];
    const int* ent_feature = (const int*)d_in[3];
    const int* sub = (const int*)d_in[4];
    const float* id_embed = (const float*)d_in[7];
    const float* gtab = (const float*)d_in[8];
    const float* atab = (const float*)d_in[9];
    const float* ltab = (const float*)d_in[10];
    const float* init_rel = (const float*)d_in[11];
    const float* W = (const float*)d_in[12];
    const float* Wr = (const float*)d_in[13];
    const float* att_src = (const float*)d_in[14];
    const float* att_dst = (const float*)d_in[15];
    const float* Wrel = (const float*)d_in[16];

    char* ws = (char*)d_ws;
    unsigned* h_b = (unsigned*)ws;                          ws += (long)N_NODES * 64 * 4;    // 25.6 MB
    unsigned* rp_b = (unsigned*)ws;                         ws += (long)NR2 * 64 * 4;
    float* rproj_att = (float*)ws;                          ws += NR2 * 2 * 4;
    float* hsrc_att = (float*)ws;                           ws += (long)N_NODES * 2 * 4;
    float* hdst_att = (float*)ws;                           ws += (long)N_NODES * 2 * 4;
    unsigned short* Wt = (unsigned short*)ws;               ws += (long)GCN * KPAD * 2;
    int* cursor = (int*)ws;                                 ws += (long)N_NODES * 4;
    uint2* ebuf = (uint2*)ws;                               ws += (long)N_NODES * CAP * 8;   // 51.2 MB

    float* out = (float*)d_out;
    float* out_sub = out;
    float* out_r = out + OUT_R_OFF;
    float* out_x = out + OUT_X_OFF;

    const int NB = (N_NODES + 255) / 256;   // 391

    wtrel_kernel<<<NR2 + NB, 256, 0, stream>>>(W, Wt, cursor, init_rel, Wr, Wrel,
                                               att_src, rp_b, rproj_att, out_r);
    hgemm_kernel<<<(N_NODES + 127) / 128, 256, 0, stream>>>(id_embed, gtab, atab, ltab,
                                                            ent_feature, Wt, att_src, att_dst,
                                                            h_b, hsrc_att, hdst_att);
    fill_kernel<<<(E_EDGES + 511) / 512, 256, 0, stream>>>(edge_index, edge_type, cursor,
                                                           (const float2*)hsrc_att,
                                                           (const float2*)rproj_att,
                                                           (const float2*)hdst_att, ebuf);
    agg_kernel<<<N_NODES / 8, 256, 0, stream>>>(cursor, ebuf, h_b, rp_b, out_x);
    gather_kernel<<<(B_SUB * GCN + 255) / 256, 256, 0, stream>>>(sub, out_x, out_sub);
}